// Round 9
// baseline (1676.928 us; speedup 1.0000x reference)
//
#include <hip/hip_runtime.h>
#include <hip/hip_bf16.h>

#define B_ 4
#define L_ 8192
#define D_ 1024
#define H_ 16
#define SCALE 0.125f
#define NC 16           // attention L-chunks (16 -> 1024 blocks, 4/CU)
#define QPAD 64         // padded query count (U=50 -> 64)
#define RS 72           // LDS row stride in ushort (64 + 8 pad)

typedef __attribute__((ext_vector_type(8))) short bf16x8;
typedef __attribute__((ext_vector_type(4))) float f32x4;

__device__ __forceinline__ void gl2lds16(const void* g, void* s) {
    __builtin_amdgcn_global_load_lds(
        (const __attribute__((address_space(1))) unsigned int*)g,
        (__attribute__((address_space(3))) unsigned int*)s, 16, 0, 0);
}

__device__ __forceinline__ unsigned short bfbits(float a) {
    __hip_bfloat16 h = __float2bfloat16(a);
    return *(unsigned short*)&h;
}
__device__ __forceinline__ float bf2f(unsigned short u) {
    return __uint_as_float(((unsigned)u) << 16);
}

// ---- split fp32 -> 3 bf16 terms ----
__global__ __launch_bounds__(256) void split3_kernel(const float* __restrict__ in,
        unsigned short* __restrict__ ph, unsigned short* __restrict__ pm,
        unsigned short* __restrict__ pl, int n4) {
    int i = blockIdx.x * 256 + threadIdx.x;
    if (i >= n4) return;
    float4 v = ((const float4*)in)[i];
    float c[4] = {v.x, v.y, v.z, v.w};
    unsigned short h[4], m[4], l[4];
    #pragma unroll
    for (int j = 0; j < 4; ++j) {
        float a = c[j];
        unsigned short hb = bfbits(a);
        float rh = a - bf2f(hb);
        unsigned short mb = bfbits(rh);
        float rm = rh - bf2f(mb);
        h[j] = hb; m[j] = mb; l[j] = bfbits(rm);
    }
    ((ushort4*)ph)[i] = *(ushort4*)h;
    ((ushort4*)pm)[i] = *(ushort4*)m;
    ((ushort4*)pl)[i] = *(ushort4*)l;
}

__global__ __launch_bounds__(256) void split2_kernel(const float* __restrict__ in,
        unsigned short* __restrict__ ph, unsigned short* __restrict__ pm, int n4) {
    int i = blockIdx.x * 256 + threadIdx.x;
    if (i >= n4) return;
    float4 v = ((const float4*)in)[i];
    float c[4] = {v.x, v.y, v.z, v.w};
    unsigned short h[4], m[4];
    #pragma unroll
    for (int j = 0; j < 4; ++j) {
        float a = c[j];
        unsigned short hb = bfbits(a);
        float rh = a - bf2f(hb);
        h[j] = hb; m[j] = bfbits(rh);
    }
    ((ushort4*)ph)[i] = *(ushort4*)h;
    ((ushort4*)pm)[i] = *(ushort4*)m;
}

// ---- xmean ----
__global__ __launch_bounds__(256) void xmean_kernel(const float* __restrict__ x,
                                                    float* __restrict__ xmean) {
    int c = blockIdx.x;
    int j = blockIdx.y * 256 + threadIdx.x;
    int b = blockIdx.z;
    const float* xp = x + ((size_t)b * L_ + (size_t)c * 256) * D_ + j;
    float s = 0.f;
    for (int l = 0; l < 256; ++l) s += xp[(size_t)l * D_];
    atomicAdd(&xmean[b * D_ + j], s * (1.0f / L_));
}

// ---- out[b][j] = dot(in[b], W[j]) + bias[j] ----
__global__ __launch_bounds__(256) void vecmat_kernel(const float* __restrict__ in,
                                                     const float* __restrict__ W,
                                                     const float* __restrict__ bias,
                                                     float* __restrict__ out) {
    __shared__ float vs[D_];
    int b = blockIdx.y;
    int j = blockIdx.x * 256 + threadIdx.x;
    for (int t = threadIdx.x; t < D_; t += 256) vs[t] = in[b * D_ + t];
    __syncthreads();
    const float* wr = W + (size_t)j * D_;
    float acc = 0.f;
    #pragma unroll 4
    for (int k = 0; k < D_; k += 4) {
        float4 w4 = *(const float4*)(wr + k);
        acc += vs[k] * w4.x + vs[k + 1] * w4.y + vs[k + 2] * w4.z + vs[k + 3] * w4.w;
    }
    out[b * D_ + j] = acc + bias[j];
}

// ---- Ksamp (fp32 exact, selection path) ----
__global__ __launch_bounds__(256) void ksamp_kernel(const float* __restrict__ x,
                                                    const float* __restrict__ Wk,
                                                    const float* __restrict__ bk,
                                                    const int* __restrict__ idx_k,
                                                    float* __restrict__ Ksamp, int U) {
    __shared__ float vs[D_];
    int u = blockIdx.x, b = blockIdx.y;
    int row = idx_k[u];
    const float* xp = x + ((size_t)b * L_ + row) * D_;
    for (int t = threadIdx.x; t < D_; t += 256) vs[t] = xp[t];
    __syncthreads();
    #pragma unroll
    for (int r = 0; r < 4; ++r) {
        int j = r * 256 + threadIdx.x;
        const float* wr = Wk + (size_t)j * D_;
        float acc = 0.f;
        #pragma unroll 4
        for (int k = 0; k < D_; k += 4) {
            float4 w4 = *(const float4*)(wr + k);
            acc += vs[k] * w4.x + vs[k + 1] * w4.y + vs[k + 2] * w4.z + vs[k + 3] * w4.w;
        }
        Ksamp[((size_t)b * U + u) * D_ + j] = acc + bk[j];
    }
}

// ---- fused QKV via split-bf16 MFMA, counted-vmcnt sub-phases (T4) ----
// Per K-step the 6 (or 4) tiles occupy DISTINCT LDS buffers, so instead of one
// vmcnt(0) drain of all 12 loads we phase: wait-own-count -> s_barrier (all
// waves issue identically, so per-wave counted wait + barrier == tile landed
// chip-wide), compute, next phase. Product order identical to round 1 ->
// bitwise-identical outputs (selection-safe).
#define TM 128
#define TN 128
#define BK 32
#define TSZ (TM * BK)

__global__ __launch_bounds__(256) void qkv_mfma(
    const unsigned short* __restrict__ xh, const unsigned short* __restrict__ xm,
    const unsigned short* __restrict__ xl,
    const unsigned short* __restrict__ qh, const unsigned short* __restrict__ qm,
    const unsigned short* __restrict__ ql,
    const unsigned short* __restrict__ kh, const unsigned short* __restrict__ km,
    const unsigned short* __restrict__ vh, const unsigned short* __restrict__ vm,
    const float* __restrict__ bq, const float* __restrict__ bk2, const float* __restrict__ bv,
    float* __restrict__ Q, __hip_bfloat16* __restrict__ Kb, __hip_bfloat16* __restrict__ Vb) {
    __shared__ __align__(16) unsigned short As[3][TSZ];
    __shared__ __align__(16) unsigned short Bs[3][TSZ];

    const int n0 = blockIdx.x * TN;
    const int m0 = blockIdx.y * TM;
    const int tid = threadIdx.x;

    const float* bias; int which; int nb;
    if (n0 < 1024)      { which = 0; nb = n0;        bias = bq;  }
    else if (n0 < 2048) { which = 1; nb = n0 - 1024; bias = bk2; }
    else                { which = 2; nb = n0 - 2048; bias = bv;  }

    const int srow = tid >> 2;
    const int scol = (tid & 3) * 8;

    const int wave = tid >> 6;
    const int lane = tid & 63;
    const int wm = (wave & 1) * 64;
    const int wn = (wave >> 1) * 64;
    const int fr = lane & 15;
    const int fk = (lane >> 4) * 8;
    const int rbase = (lane >> 4) * 4;

    f32x4 acc[4][4];
    #pragma unroll
    for (int i = 0; i < 4; ++i)
        #pragma unroll
        for (int j = 0; j < 4; ++j)
            acc[i][j] = (f32x4){0.f, 0.f, 0.f, 0.f};

    const size_t aBase = (size_t)(m0 + srow) * D_ + scol;
    const size_t bBase = (size_t)(nb + srow) * D_ + scol;

    bf16x8 af[4], bfv[4];
    auto loadA = [&](const unsigned short* t) {
        #pragma unroll
        for (int i = 0; i < 4; ++i)
            af[i] = *(const bf16x8*)(t + (wm + i * 16 + fr) * BK + fk);
    };
    auto loadB = [&](const unsigned short* t) {
        #pragma unroll
        for (int j = 0; j < 4; ++j)
            bfv[j] = *(const bf16x8*)(t + (wn + j * 16 + fr) * BK + fk);
    };
    auto prod = [&]() {
        #pragma unroll
        for (int i = 0; i < 4; ++i)
            #pragma unroll
            for (int j = 0; j < 4; ++j)
                acc[i][j] = __builtin_amdgcn_mfma_f32_16x16x32_bf16(
                    af[i], bfv[j], acc[i][j], 0, 0, 0);
    };
    auto stage = [&](const unsigned short* g, unsigned short* s, int kt, size_t base) {
        gl2lds16(g + base + kt, s + tid * 8);
        gl2lds16(g + base + (size_t)64 * D_ + kt, s + tid * 8 + 2048);
    };
    // pin VMEM issue order at group boundaries so vmcnt counts map to tiles
    auto fence = []() { asm volatile("" ::: "memory"); };

    if (which == 0) {
        for (int kt = 0; kt < D_; kt += BK) {
            // issue groups: {xh,qh}=4, {qm,xm}=4, {ql,xl}=4 vmcnt units
            stage(xh, &As[0][0], kt, aBase);
            stage(qh, &Bs[0][0], kt, bBase);
            fence();
            stage(qm, &Bs[1][0], kt, bBase);
            stage(xm, &As[1][0], kt, aBase);
            fence();
            stage(ql, &Bs[2][0], kt, bBase);
            stage(xl, &As[2][0], kt, aBase);

            asm volatile("s_waitcnt vmcnt(8)" ::: "memory");  // xh,qh landed
            __builtin_amdgcn_s_barrier();
            loadA(&As[0][0]); loadB(&Bs[0][0]); prod();       // xh*qh

            asm volatile("s_waitcnt vmcnt(4)" ::: "memory");  // +qm,xm landed
            __builtin_amdgcn_s_barrier();
            loadB(&Bs[1][0]); prod();                         // xh*qm

            asm volatile("s_waitcnt vmcnt(0)" ::: "memory");  // +ql,xl landed
            __builtin_amdgcn_s_barrier();
            loadB(&Bs[2][0]); prod();                         // xh*ql
            loadA(&As[1][0]); loadB(&Bs[0][0]); prod();       // xm*qh
            loadB(&Bs[1][0]); prod();                         // xm*qm
            loadA(&As[2][0]); loadB(&Bs[0][0]); prod();       // xl*qh

            __syncthreads();   // all reads done before next-kt overwrite
        }
    } else {
        const unsigned short* Bh = (which == 1) ? kh : vh;
        const unsigned short* Bm = (which == 1) ? km : vm;
        for (int kt = 0; kt < D_; kt += BK) {
            stage(xh, &As[0][0], kt, aBase);
            stage(Bh, &Bs[0][0], kt, bBase);
            fence();
            stage(Bm, &Bs[1][0], kt, bBase);
            stage(xm, &As[1][0], kt, aBase);

            asm volatile("s_waitcnt vmcnt(4)" ::: "memory");  // xh,Bh landed
            __builtin_amdgcn_s_barrier();
            loadA(&As[0][0]); loadB(&Bs[0][0]); prod();       // xh*Bh

            asm volatile("s_waitcnt vmcnt(0)" ::: "memory");  // +Bm,xm landed
            __builtin_amdgcn_s_barrier();
            loadB(&Bs[1][0]); prod();                         // xh*Bm
            loadA(&As[1][0]); loadB(&Bs[0][0]); prod();       // xm*Bh

            __syncthreads();
        }
    }

    float biasv[4];
    #pragma unroll
    for (int j = 0; j < 4; ++j) biasv[j] = bias[nb + wn + j * 16 + fr];

    #pragma unroll
    for (int i = 0; i < 4; ++i) {
        #pragma unroll
        for (int r = 0; r < 4; ++r) {
            size_t row = (size_t)(m0 + wm + i * 16 + rbase + r);
            #pragma unroll
            for (int j = 0; j < 4; ++j) {
                float v = acc[i][j][r] + biasv[j];
                int n = nb + wn + j * 16 + fr;
                if (which == 0)      Q[row * D_ + n] = v;
                else if (which == 1) Kb[row * D_ + n] = __float2bfloat16(v);
                else                 Vb[row * D_ + n] = __float2bfloat16(v);
            }
        }
    }
}

// ---- M[b][h][l] ----
__global__ __launch_bounds__(256) void m_kernel(const float* __restrict__ Q,
                                                const float* __restrict__ Ksamp,
                                                float* __restrict__ M, int U) {
    __shared__ float ks[64 * 64];
    int lc = blockIdx.x, h = blockIdx.y, b = blockIdx.z;
    for (int t = threadIdx.x; t < U * 64; t += 256) {
        int u = t >> 6, d = t & 63;
        ks[t] = Ksamp[((size_t)b * U + u) * D_ + h * 64 + d];
    }
    __syncthreads();
    int l = lc * 256 + threadIdx.x;
    const float* qp = Q + ((size_t)b * L_ + l) * D_ + h * 64;
    float q[64];
    #pragma unroll
    for (int i = 0; i < 16; ++i) *(float4*)&q[i * 4] = *(const float4*)(qp + i * 4);
    float mx = -INFINITY, sm = 0.f;
    for (int u = 0; u < U; ++u) {
        const float* kp = &ks[u * 64];
        float dot = 0.f;
        #pragma unroll
        for (int d = 0; d < 64; ++d) dot = fmaf(q[d], kp[d], dot);
        dot *= SCALE;
        mx = fmaxf(mx, dot);
        sm += dot;
    }
    M[((size_t)(b * H_ + h)) * L_ + l] = mx - sm / (float)U;
}

// ---- top-k via exact radix select (top-U set; ties -> lower index) ----
__global__ __launch_bounds__(256) void topk_kernel(const float* __restrict__ M,
                                                   int* __restrict__ topidx, int U) {
    __shared__ unsigned keys[L_];
    __shared__ int      eqlist[L_];
    __shared__ int      hist[256];
    __shared__ unsigned sprefix;
    __shared__ int      sneed, cgt, ceq;

    const int bh = blockIdx.x;
    const int tid = threadIdx.x;
    const float* mp = M + (size_t)bh * L_;

    for (int t = tid; t < L_; t += 256) {
        unsigned s = __float_as_uint(mp[t]);
        keys[t] = (s & 0x80000000u) ? ~s : (s | 0x80000000u);
    }
    if (tid == 0) { cgt = 0; ceq = 0; }
    __syncthreads();

    unsigned prefix = 0;
    int need = U;
    for (int shift = 24; shift >= 0; shift -= 8) {
        hist[tid] = 0;
        __syncthreads();
        for (int t = tid; t < L_; t += 256) {
            unsigned k = keys[t];
            bool ok = (shift == 24) ||
                      ((k >> (shift + 8)) == (prefix >> (shift + 8)));
            if (ok) atomicAdd(&hist[(k >> shift) & 255], 1);
        }
        __syncthreads();
        if (tid == 0) {
            int acc = 0, b = 255;
            for (; b > 0; --b) {
                if (acc + hist[b] >= need) break;
                acc += hist[b];
            }
            sneed = need - acc;
            sprefix = prefix | ((unsigned)b << shift);
        }
        __syncthreads();
        prefix = sprefix;
        need = sneed;
        __syncthreads();
    }
    const unsigned vkey = prefix;

    for (int t = tid; t < L_; t += 256) {
        unsigned k = keys[t];
        if (k > vkey) {
            int pos = atomicAdd(&cgt, 1);
            topidx[bh * U + pos] = t;
        } else if (k == vkey) {
            int p = atomicAdd(&ceq, 1);
            eqlist[p] = t;
        }
    }
    __syncthreads();
    const int s = ceq, r = need, base = U - r;
    for (int i = tid; i < s; i += 256) {
        int mine = eqlist[i], rank = 0;
        for (int j = 0; j < s; ++j) rank += (eqlist[j] < mine);
        if (rank < r) topidx[bh * U + base + rank] = mine;
    }
}

// ---- MFMA flash attention: all U queries of one (b,h) share each K/V tile ----
__global__ __launch_bounds__(256) void attn_mfma(const float* __restrict__ Q,
        const __hip_bfloat16* __restrict__ Kb, const __hip_bfloat16* __restrict__ Vb,
        const int* __restrict__ topidx,
        float* __restrict__ part_m, float* __restrict__ part_s,
        float* __restrict__ part_acc, int U) {
    __shared__ __align__(16) unsigned short Qh[QPAD * RS];
    __shared__ __align__(16) unsigned short Qm[QPAD * RS];
    __shared__ __align__(16) unsigned short Ks[64 * RS];
    __shared__ __align__(16) unsigned short Vt[64 * RS];
    __shared__ __align__(16) unsigned short Ph[QPAD * RS];

    const int c = blockIdx.x, h = blockIdx.y, b = blockIdx.z;
    const int bh = b * H_ + h;
    const int tid = threadIdx.x;
    const int wave = tid >> 6, lane = tid & 63;
    const int w16 = wave * 16;
    const int fr = lane & 15;
    const int quad = lane >> 4;
    const int fk = quad * 8;
    const int l0 = c * (L_ / NC);

    {
        int u = tid >> 2;
        int d0 = (tid & 3) * 16;
        unsigned short hbuf[16], mbuf[16];
        if (u < U) {
            int row = topidx[bh * U + u];
            const float* qp = Q + ((size_t)b * L_ + row) * D_ + h * 64 + d0;
            #pragma unroll
            for (int i = 0; i < 16; ++i) {
                float v = qp[i] * SCALE;
                unsigned short hb = bfbits(v);
                hbuf[i] = hb;
                mbuf[i] = bfbits(v - bf2f(hb));
            }
        } else {
            #pragma unroll
            for (int i = 0; i < 16; ++i) { hbuf[i] = 0; mbuf[i] = 0; }
        }
        #pragma unroll
        for (int i = 0; i < 2; ++i) {
            *(uint4*)&Qh[u * RS + d0 + i * 8] = ((uint4*)hbuf)[i];
            *(uint4*)&Qm[u * RS + d0 + i * 8] = ((uint4*)mbuf)[i];
        }
    }

    const int kkey = tid >> 3, kd0 = (tid & 7) * 8;
    const int vkey = tid >> 2, vd0 = (tid & 3) * 16;
    const __hip_bfloat16* kbase = Kb + ((size_t)b * L_ + l0) * D_ + h * 64;
    const __hip_bfloat16* vbase = Vb + ((size_t)b * L_ + l0) * D_ + h * 64;

    uint4 kr0, kr1, vr0, vr1;
    auto loadKV = [&](int t) {
        const __hip_bfloat16* kp = kbase + (size_t)t * 64 * D_;
        const __hip_bfloat16* vp = vbase + (size_t)t * 64 * D_ + (size_t)vkey * D_ + vd0;
        kr0 = *(const uint4*)(kp + (size_t)kkey * D_ + kd0);
        kr1 = *(const uint4*)(kp + (size_t)(kkey + 32) * D_ + kd0);
        vr0 = *(const uint4*)(vp);
        vr1 = *(const uint4*)(vp + 8);
    };
    auto writeKV = [&]() {
        *(uint4*)&Ks[kkey * RS + kd0] = kr0;
        *(uint4*)&Ks[(kkey + 32) * RS + kd0] = kr1;
        unsigned short vb_[16];
        *(uint4*)&vb_[0] = vr0;
        *(uint4*)&vb_[8] = vr1;
        #pragma unroll
        for (int i = 0; i < 16; ++i) Vt[(vd0 + i) * RS + vkey] = vb_[i];
    };

    float m_r[4], s_r[4];
    f32x4 acc_o[4];
    #pragma unroll
    for (int r = 0; r < 4; ++r) { m_r[r] = -INFINITY; s_r[r] = 0.f; }
    #pragma unroll
    for (int n = 0; n < 4; ++n) acc_o[n] = (f32x4){0.f, 0.f, 0.f, 0.f};

    loadKV(0);
    writeKV();
    __syncthreads();

    const int NT = (L_ / NC) / 64;
    for (int t = 0; t < NT; ++t) {
        if (t + 1 < NT) loadKV(t + 1);

        f32x4 sacc[4];
        __builtin_amdgcn_s_setprio(1);
        #pragma unroll
        for (int n = 0; n < 4; ++n) {
            sacc[n] = (f32x4){0.f, 0.f, 0.f, 0.f};
            #pragma unroll
            for (int ks = 0; ks < 2; ++ks) {
                int k0 = ks * 32;
                bf16x8 ah = *(const bf16x8*)&Qh[(w16 + fr) * RS + k0 + fk];
                bf16x8 am = *(const bf16x8*)&Qm[(w16 + fr) * RS + k0 + fk];
                bf16x8 bb = *(const bf16x8*)&Ks[(n * 16 + fr) * RS + k0 + fk];
                sacc[n] = __builtin_amdgcn_mfma_f32_16x16x32_bf16(ah, bb, sacc[n], 0, 0, 0);
                sacc[n] = __builtin_amdgcn_mfma_f32_16x16x32_bf16(am, bb, sacc[n], 0, 0, 0);
            }
        }
        __builtin_amdgcn_s_setprio(0);

        float p[4][4];
        #pragma unroll
        for (int r = 0; r < 4; ++r) {
            float rowmax = fmaxf(fmaxf(sacc[0][r], sacc[1][r]),
                                 fmaxf(sacc[2][r], sacc[3][r]));
            #pragma unroll
            for (int msk = 1; msk <= 8; msk <<= 1)
                rowmax = fmaxf(rowmax, __shfl_xor(rowmax, msk, 64));
            float mnew = fmaxf(m_r[r], rowmax);
            float alpha = __expf(m_r[r] - mnew);
            float rowsum = 0.f;
            #pragma unroll
            for (int n = 0; n < 4; ++n) {
                p[n][r] = __expf(sacc[n][r] - mnew);
                rowsum += p[n][r];
            }
            #pragma unroll
            for (int msk = 1; msk <= 8; msk <<= 1)
                rowsum += __shfl_xor(rowsum, msk, 64);
            s_r[r] = s_r[r] * alpha + rowsum;
            m_r[r] = mnew;
            #pragma unroll
            for (int n = 0; n < 4; ++n) acc_o[n][r] *= alpha;
        }

        #pragma unroll
        for (int r = 0; r < 4; ++r)
            #pragma unroll
            for (int n = 0; n < 4; ++n)
                Ph[(w16 + quad * 4 + r) * RS + n * 16 + fr] = bfbits(p[n][r]);

        __builtin_amdgcn_s_setprio(1);
        #pragma unroll
        for (int n = 0; n < 4; ++n) {
            #pragma unroll
            for (int ks = 0; ks < 2; ++ks) {
                int k0 = ks * 32;
                bf16x8 pa = *(const bf16x8*)&Ph[(w16 + fr) * RS + k0 + fk];
                bf16x8 vb = *(const bf16x8*)&Vt[(n * 16 + fr) * RS + k0 + fk];
                acc_o[n] = __builtin_amdgcn_mfma_f32_16x16x32_bf16(pa, vb, acc_o[n], 0, 0, 0);
            }
        }
        __builtin_amdgcn_s_setprio(0);

        if (t + 1 < NT) {
            __syncthreads();
            writeKV();
            __syncthreads();
        }
    }

    #pragma unroll
    for (int r = 0; r < 4; ++r) {
        int q = w16 + quad * 4 + r;
        if (q < U) {
            size_t base = ((size_t)(bh * QPAD + q)) * NC + c;
            if (fr == 0) { part_m[base] = m_r[r]; part_s[base] = s_r[r]; }
            #pragma unroll
            for (int n = 0; n < 4; ++n)
                part_acc[base * 64 + n * 16 + fr] = acc_o[n][r];
        }
    }
}

// ---- merge NC chunk partials -> ctx_top ----
__global__ __launch_bounds__(64) void attn_combine(const float* __restrict__ part_m,
        const float* __restrict__ part_s, const float* __restrict__ part_acc,
        float* __restrict__ ctx_top, int U) {
    int u = blockIdx.x, h = blockIdx.y, b = blockIdx.z;
    int bh = b * H_ + h;
    int d = threadIdx.x;
    size_t base = ((size_t)(bh * QPAD + u)) * NC;
    float M = -INFINITY;
    #pragma unroll
    for (int c = 0; c < NC; ++c) M = fmaxf(M, part_m[base + c]);
    float S = 0.f, A = 0.f;
    #pragma unroll
    for (int c = 0; c < NC; ++c) {
        float f = __expf(part_m[base + c] - M);
        S += part_s[base + c] * f;
        A += part_acc[(base + c) * 64 + d] * f;
    }
    ctx_top[(((size_t)bh) * U + u) * 64 + d] = A / S;
}

// ---- out[b][l][:] = base[b][:] ----
__global__ __launch_bounds__(256) void fill_base_kernel(const float* __restrict__ base,
                                                        float* __restrict__ out) {
    size_t i = (size_t)blockIdx.x * 256 + threadIdx.x;
    int col4 = (int)(i & 255);
    int b = (int)(i >> 21);
    ((float4*)out)[i] = ((const float4*)base)[b * 256 + col4];
}

// ---- out[b][row][:] += (ctx_top - vmean_h) @ Wo_h.T ----
__global__ __launch_bounds__(256) void delta_kernel(const float* __restrict__ ctx_top,
        const float* __restrict__ vmean, const float* __restrict__ Wo,
        const int* __restrict__ topidx, float* __restrict__ out, int U) {
    __shared__ float cd[64];
    int u = blockIdx.x, h = blockIdx.y, b = blockIdx.z;
    int row = topidx[(b * H_ + h) * U + u];
    if (threadIdx.x < 64) {
        cd[threadIdx.x] = ctx_top[(((size_t)(b * H_ + h)) * U + u) * 64 + threadIdx.x]
                        - vmean[b * D_ + h * 64 + threadIdx.x];
    }
    __syncthreads();
    float* op = out + ((size_t)b * L_ + row) * D_;
    #pragma unroll
    for (int r = 0; r < 4; ++r) {
        int j = r * 256 + threadIdx.x;
        const float* wr = Wo + (size_t)j * D_ + h * 64;
        float dlt = 0.f;
        #pragma unroll
        for (int k = 0; k < 64; k += 4) {
            float4 w4 = *(const float4*)(wr + k);
            dlt += cd[k] * w4.x + cd[k + 1] * w4.y + cd[k + 2] * w4.z + cd[k + 3] * w4.w;
        }
        atomicAdd(op + j, dlt);
    }
}

extern "C" void kernel_launch(void* const* d_in, const int* in_sizes, int n_in,
                              void* d_out, int out_size, void* d_ws, size_t ws_size,
                              hipStream_t stream) {
    const float* x   = (const float*)d_in[0];
    const float* Wq  = (const float*)d_in[1];
    const float* bq  = (const float*)d_in[2];
    const float* Wk  = (const float*)d_in[3];
    const float* bk  = (const float*)d_in[4];
    const float* Wv  = (const float*)d_in[5];
    const float* bv  = (const float*)d_in[6];
    const float* Wo  = (const float*)d_in[7];
    const float* bo  = (const float*)d_in[8];
    const int* idx_k = (const int*)d_in[9];
    const int U = in_sizes[9];
    float* out = (float*)d_out;
    (void)n_in; (void)ws_size;

    char* ws = (char*)d_ws;
    size_t off = 0;
    auto alloc = [&](size_t bytes) -> void* {
        void* p = ws + off;
        off += (bytes + 255) & ~(size_t)255;
        return p;
    };
    float* Q              = (float*)alloc((size_t)B_ * L_ * D_ * 4);
    __hip_bfloat16* Kb    = (__hip_bfloat16*)alloc((size_t)B_ * L_ * D_ * 2);
    __hip_bfloat16* Vb    = (__hip_bfloat16*)alloc((size_t)B_ * L_ * D_ * 2);
    unsigned short* xh    = (unsigned short*)alloc((size_t)B_ * L_ * D_ * 2);
    unsigned short* xm    = (unsigned short*)alloc((size_t)B_ * L_ * D_ * 2);
    unsigned short* xl    = (unsigned short*)alloc((size_t)B_ * L_ * D_ * 2);
    unsigned short* wqh   = (unsigned short*)alloc((size_t)D_ * D_ * 2);
    unsigned short* wqm   = (unsigned short*)alloc((size_t)D_ * D_ * 2);
    unsigned short* wql   = (unsigned short*)alloc((size_t)D_ * D_ * 2);
    unsigned short* wkh   = (unsigned short*)alloc((size_t)D_ * D_ * 2);
    unsigned short* wkm   = (unsigned short*)alloc((size_t)D_ * D_ * 2);
    unsigned short* wvh   = (unsigned short*)alloc((size_t)D_ * D_ * 2);
    unsigned short* wvm   = (unsigned short*)alloc((size_t)D_ * D_ * 2);
    float* Ksamp          = (float*)alloc((size_t)B_ * 64 * D_ * 4);
    float* Mbuf           = (float*)alloc((size_t)B_ * H_ * L_ * 4);
    int*   topidx         = (int*)alloc((size_t)B_ * H_ * 64 * 4);
    float* xmean          = (float*)alloc((size_t)B_ * D_ * 4);
    float* vmean          = (float*)alloc((size_t)B_ * D_ * 4);
    float* base           = (float*)alloc((size_t)B_ * D_ * 4);
    float* ctxt           = (float*)alloc((size_t)B_ * H_ * 64 * 64 * 4);
    float* part_m         = (float*)alloc((size_t)B_ * H_ * QPAD * NC * 4);
    float* part_s         = (float*)alloc((size_t)B_ * H_ * QPAD * NC * 4);
    float* part_acc       = (float*)alloc((size_t)B_ * H_ * QPAD * NC * 64 * 4);

    hipMemsetAsync(xmean, 0, (size_t)B_ * D_ * 4, stream);
    xmean_kernel<<<dim3(32, 4, B_), 256, 0, stream>>>(x, xmean);
    vecmat_kernel<<<dim3(4, B_), 256, 0, stream>>>(xmean, Wv, bv, vmean);
    vecmat_kernel<<<dim3(4, B_), 256, 0, stream>>>(vmean, Wo, bo, base);
    ksamp_kernel<<<dim3(U, B_), 256, 0, stream>>>(x, Wk, bk, idx_k, Ksamp, U);

    const int n4x = B_ * L_ * D_ / 4;
    const int n4w = D_ * D_ / 4;
    split3_kernel<<<dim3(n4x / 256), 256, 0, stream>>>(x, xh, xm, xl, n4x);
    split3_kernel<<<dim3(n4w / 256), 256, 0, stream>>>(Wq, wqh, wqm, wql, n4w);
    split2_kernel<<<dim3(n4w / 256), 256, 0, stream>>>(Wk, wkh, wkm, n4w);
    split2_kernel<<<dim3(n4w / 256), 256, 0, stream>>>(Wv, wvh, wvm, n4w);

    qkv_mfma<<<dim3(24, 256), 256, 0, stream>>>(xh, xm, xl, wqh, wqm, wql,
                                                wkh, wkm, wvh, wvm,
                                                bq, bk, bv, Q, Kb, Vb);

    m_kernel<<<dim3(32, H_, B_), 256, 0, stream>>>(Q, Ksamp, Mbuf, U);
    topk_kernel<<<dim3(B_ * H_), 256, 0, stream>>>(Mbuf, topidx, U);
    attn_mfma<<<dim3(NC, H_, B_), 256, 0, stream>>>(Q, Kb, Vb, topidx,
                                                    part_m, part_s, part_acc, U);
    attn_combine<<<dim3(U, H_, B_), 64, 0, stream>>>(part_m, part_s, part_acc, ctxt, U);
    fill_base_kernel<<<dim3(out_size / 4 / 256), 256, 0, stream>>>(base, out);
    delta_kernel<<<dim3(U, H_, B_), 256, 0, stream>>>(ctxt, vmean, Wo, topidx, out, U);
}

// Round 10
// 1605.886 us; speedup vs baseline: 1.0442x; 1.0442x over previous
//
#include <hip/hip_runtime.h>
#include <hip/hip_bf16.h>

#define B_ 4
#define L_ 8192
#define D_ 1024
#define H_ 16
#define SCALE 0.125f
#define NC 16           // attention L-chunks (16 -> 1024 blocks, 4/CU)
#define QPAD 64         // padded query count (U=50 -> 64)
#define RS 72           // LDS row stride in ushort (64 + 8 pad)

typedef __attribute__((ext_vector_type(8))) short bf16x8;
typedef __attribute__((ext_vector_type(4))) float f32x4;

__device__ __forceinline__ void gl2lds16(const void* g, void* s) {
    __builtin_amdgcn_global_load_lds(
        (const __attribute__((address_space(1))) unsigned int*)g,
        (__attribute__((address_space(3))) unsigned int*)s, 16, 0, 0);
}

__device__ __forceinline__ unsigned short bfbits(float a) {
    __hip_bfloat16 h = __float2bfloat16(a);
    return *(unsigned short*)&h;
}
__device__ __forceinline__ float bf2f(unsigned short u) {
    return __uint_as_float(((unsigned)u) << 16);
}

// ---- split fp32 -> 3 bf16 terms ----
__global__ __launch_bounds__(256) void split3_kernel(const float* __restrict__ in,
        unsigned short* __restrict__ ph, unsigned short* __restrict__ pm,
        unsigned short* __restrict__ pl, int n4) {
    int i = blockIdx.x * 256 + threadIdx.x;
    if (i >= n4) return;
    float4 v = ((const float4*)in)[i];
    float c[4] = {v.x, v.y, v.z, v.w};
    unsigned short h[4], m[4], l[4];
    #pragma unroll
    for (int j = 0; j < 4; ++j) {
        float a = c[j];
        unsigned short hb = bfbits(a);
        float rh = a - bf2f(hb);
        unsigned short mb = bfbits(rh);
        float rm = rh - bf2f(mb);
        h[j] = hb; m[j] = mb; l[j] = bfbits(rm);
    }
    ((ushort4*)ph)[i] = *(ushort4*)h;
    ((ushort4*)pm)[i] = *(ushort4*)m;
    ((ushort4*)pl)[i] = *(ushort4*)l;
}

__global__ __launch_bounds__(256) void split2_kernel(const float* __restrict__ in,
        unsigned short* __restrict__ ph, unsigned short* __restrict__ pm, int n4) {
    int i = blockIdx.x * 256 + threadIdx.x;
    if (i >= n4) return;
    float4 v = ((const float4*)in)[i];
    float c[4] = {v.x, v.y, v.z, v.w};
    unsigned short h[4], m[4];
    #pragma unroll
    for (int j = 0; j < 4; ++j) {
        float a = c[j];
        unsigned short hb = bfbits(a);
        float rh = a - bf2f(hb);
        h[j] = hb; m[j] = bfbits(rh);
    }
    ((ushort4*)ph)[i] = *(ushort4*)h;
    ((ushort4*)pm)[i] = *(ushort4*)m;
}

// ---- xmean ----
__global__ __launch_bounds__(256) void xmean_kernel(const float* __restrict__ x,
                                                    float* __restrict__ xmean) {
    int c = blockIdx.x;
    int j = blockIdx.y * 256 + threadIdx.x;
    int b = blockIdx.z;
    const float* xp = x + ((size_t)b * L_ + (size_t)c * 256) * D_ + j;
    float s = 0.f;
    for (int l = 0; l < 256; ++l) s += xp[(size_t)l * D_];
    atomicAdd(&xmean[b * D_ + j], s * (1.0f / L_));
}

// ---- out[b][j] = dot(in[b], W[j]) + bias[j] ----
__global__ __launch_bounds__(256) void vecmat_kernel(const float* __restrict__ in,
                                                     const float* __restrict__ W,
                                                     const float* __restrict__ bias,
                                                     float* __restrict__ out) {
    __shared__ float vs[D_];
    int b = blockIdx.y;
    int j = blockIdx.x * 256 + threadIdx.x;
    for (int t = threadIdx.x; t < D_; t += 256) vs[t] = in[b * D_ + t];
    __syncthreads();
    const float* wr = W + (size_t)j * D_;
    float acc = 0.f;
    #pragma unroll 4
    for (int k = 0; k < D_; k += 4) {
        float4 w4 = *(const float4*)(wr + k);
        acc += vs[k] * w4.x + vs[k + 1] * w4.y + vs[k + 2] * w4.z + vs[k + 3] * w4.w;
    }
    out[b * D_ + j] = acc + bias[j];
}

// ---- Ksamp (fp32 exact, selection path); row-parallel over blockIdx.z ----
__global__ __launch_bounds__(256) void ksamp_kernel(const float* __restrict__ x,
                                                    const float* __restrict__ Wk,
                                                    const float* __restrict__ bk,
                                                    const int* __restrict__ idx_k,
                                                    float* __restrict__ Ksamp, int U) {
    __shared__ float vs[D_];
    int u = blockIdx.x, b = blockIdx.y, r = blockIdx.z;
    int row = idx_k[u];
    const float* xp = x + ((size_t)b * L_ + row) * D_;
    for (int t = threadIdx.x; t < D_; t += 256) vs[t] = xp[t];
    __syncthreads();
    int j = r * 256 + threadIdx.x;
    const float* wr = Wk + (size_t)j * D_;
    float acc = 0.f;
    #pragma unroll 4
    for (int k = 0; k < D_; k += 4) {
        float4 w4 = *(const float4*)(wr + k);
        acc += vs[k] * w4.x + vs[k + 1] * w4.y + vs[k + 2] * w4.z + vs[k + 3] * w4.w;
    }
    Ksamp[((size_t)b * U + u) * D_ + j] = acc + bk[j];
}

// ---- fused QKV via split-bf16 MFMA (round-7 measured structure: ~865 us) ----
#define TM 128
#define TN 128
#define BK 32
#define TSZ (TM * BK)

__global__ __launch_bounds__(256) void qkv_mfma(
    const unsigned short* __restrict__ xh, const unsigned short* __restrict__ xm,
    const unsigned short* __restrict__ xl,
    const unsigned short* __restrict__ qh, const unsigned short* __restrict__ qm,
    const unsigned short* __restrict__ ql,
    const unsigned short* __restrict__ kh, const unsigned short* __restrict__ km,
    const unsigned short* __restrict__ vh, const unsigned short* __restrict__ vm,
    const float* __restrict__ bq, const float* __restrict__ bk2, const float* __restrict__ bv,
    float* __restrict__ Q, __hip_bfloat16* __restrict__ Kb, __hip_bfloat16* __restrict__ Vb) {
    __shared__ __align__(16) unsigned short As[3][TSZ];
    __shared__ __align__(16) unsigned short Bs[3][TSZ];

    const int n0 = blockIdx.x * TN;
    const int m0 = blockIdx.y * TM;
    const int tid = threadIdx.x;

    const float* bias; int which; int nb;
    if (n0 < 1024)      { which = 0; nb = n0;        bias = bq;  }
    else if (n0 < 2048) { which = 1; nb = n0 - 1024; bias = bk2; }
    else                { which = 2; nb = n0 - 2048; bias = bv;  }

    const int srow = tid >> 2;
    const int scol = (tid & 3) * 8;

    const int wave = tid >> 6;
    const int lane = tid & 63;
    const int wm = (wave & 1) * 64;
    const int wn = (wave >> 1) * 64;
    const int fr = lane & 15;
    const int fk = (lane >> 4) * 8;
    const int rbase = (lane >> 4) * 4;

    f32x4 acc[4][4];
    #pragma unroll
    for (int i = 0; i < 4; ++i)
        #pragma unroll
        for (int j = 0; j < 4; ++j)
            acc[i][j] = (f32x4){0.f, 0.f, 0.f, 0.f};

    const size_t aBase = (size_t)(m0 + srow) * D_ + scol;
    const size_t bBase = (size_t)(nb + srow) * D_ + scol;

    bf16x8 af[4], bfv[4];
    auto loadA = [&](const unsigned short* t) {
        #pragma unroll
        for (int i = 0; i < 4; ++i)
            af[i] = *(const bf16x8*)(t + (wm + i * 16 + fr) * BK + fk);
    };
    auto loadB = [&](const unsigned short* t) {
        #pragma unroll
        for (int j = 0; j < 4; ++j)
            bfv[j] = *(const bf16x8*)(t + (wn + j * 16 + fr) * BK + fk);
    };
    auto prod = [&]() {
        #pragma unroll
        for (int i = 0; i < 4; ++i)
            #pragma unroll
            for (int j = 0; j < 4; ++j)
                acc[i][j] = __builtin_amdgcn_mfma_f32_16x16x32_bf16(
                    af[i], bfv[j], acc[i][j], 0, 0, 0);
    };
    auto stage = [&](const unsigned short* g, unsigned short* s, int kt, size_t base) {
        gl2lds16(g + base + kt, s + tid * 8);
        gl2lds16(g + base + (size_t)64 * D_ + kt, s + tid * 8 + 2048);
    };

    if (which == 0) {
        // Q: xh*qh + xh*qm + xh*ql + xm*qh + xm*qm + xl*qh   (96 MFMA/barrier)
        for (int kt = 0; kt < D_; kt += BK) {
            stage(xh, &As[0][0], kt, aBase);
            stage(xm, &As[1][0], kt, aBase);
            stage(xl, &As[2][0], kt, aBase);
            stage(qh, &Bs[0][0], kt, bBase);
            stage(qm, &Bs[1][0], kt, bBase);
            stage(ql, &Bs[2][0], kt, bBase);
            __syncthreads();
            loadA(&As[0][0]); loadB(&Bs[0][0]); prod();
            loadB(&Bs[1][0]); prod();
            loadB(&Bs[2][0]); prod();
            loadA(&As[1][0]); loadB(&Bs[0][0]); prod();
            loadB(&Bs[1][0]); prod();
            loadA(&As[2][0]); loadB(&Bs[0][0]); prod();
            __syncthreads();
        }
    } else {
        // K/V: xh*Bh + xh*Bm + xm*Bh   (48 MFMA/barrier)
        const unsigned short* Bh = (which == 1) ? kh : vh;
        const unsigned short* Bm = (which == 1) ? km : vm;
        for (int kt = 0; kt < D_; kt += BK) {
            stage(xh, &As[0][0], kt, aBase);
            stage(xm, &As[1][0], kt, aBase);
            stage(Bh, &Bs[0][0], kt, bBase);
            stage(Bm, &Bs[1][0], kt, bBase);
            __syncthreads();
            loadA(&As[0][0]); loadB(&Bs[0][0]); prod();
            loadB(&Bs[1][0]); prod();
            loadA(&As[1][0]); loadB(&Bs[0][0]); prod();
            __syncthreads();
        }
    }

    float biasv[4];
    #pragma unroll
    for (int j = 0; j < 4; ++j) biasv[j] = bias[nb + wn + j * 16 + fr];

    #pragma unroll
    for (int i = 0; i < 4; ++i) {
        #pragma unroll
        for (int r = 0; r < 4; ++r) {
            size_t row = (size_t)(m0 + wm + i * 16 + rbase + r);
            #pragma unroll
            for (int j = 0; j < 4; ++j) {
                float v = acc[i][j][r] + biasv[j];
                int n = nb + wn + j * 16 + fr;
                if (which == 0)      Q[row * D_ + n] = v;
                else if (which == 1) Kb[row * D_ + n] = __float2bfloat16(v);
                else                 Vb[row * D_ + n] = __float2bfloat16(v);
            }
        }
    }
}

// ---- M[b][h][l] ----
__global__ __launch_bounds__(256) void m_kernel(const float* __restrict__ Q,
                                                const float* __restrict__ Ksamp,
                                                float* __restrict__ M, int U) {
    __shared__ float ks[64 * 64];
    int lc = blockIdx.x, h = blockIdx.y, b = blockIdx.z;
    for (int t = threadIdx.x; t < U * 64; t += 256) {
        int u = t >> 6, d = t & 63;
        ks[t] = Ksamp[((size_t)b * U + u) * D_ + h * 64 + d];
    }
    __syncthreads();
    int l = lc * 256 + threadIdx.x;
    const float* qp = Q + ((size_t)b * L_ + l) * D_ + h * 64;
    float q[64];
    #pragma unroll
    for (int i = 0; i < 16; ++i) *(float4*)&q[i * 4] = *(const float4*)(qp + i * 4);
    float mx = -INFINITY, sm = 0.f;
    for (int u = 0; u < U; ++u) {
        const float* kp = &ks[u * 64];
        float dot = 0.f;
        #pragma unroll
        for (int d = 0; d < 64; ++d) dot = fmaf(q[d], kp[d], dot);
        dot *= SCALE;
        mx = fmaxf(mx, dot);
        sm += dot;
    }
    M[((size_t)(b * H_ + h)) * L_ + l] = mx - sm / (float)U;
}

// ---- top-k via exact radix select (top-U set; ties -> lower index) ----
__global__ __launch_bounds__(256) void topk_kernel(const float* __restrict__ M,
                                                   int* __restrict__ topidx, int U) {
    __shared__ unsigned keys[L_];
    __shared__ int      eqlist[L_];
    __shared__ int      hist[256];
    __shared__ unsigned sprefix;
    __shared__ int      sneed, cgt, ceq;

    const int bh = blockIdx.x;
    const int tid = threadIdx.x;
    const float* mp = M + (size_t)bh * L_;

    for (int t = tid; t < L_; t += 256) {
        unsigned s = __float_as_uint(mp[t]);
        keys[t] = (s & 0x80000000u) ? ~s : (s | 0x80000000u);
    }
    if (tid == 0) { cgt = 0; ceq = 0; }
    __syncthreads();

    unsigned prefix = 0;
    int need = U;
    for (int shift = 24; shift >= 0; shift -= 8) {
        hist[tid] = 0;
        __syncthreads();
        for (int t = tid; t < L_; t += 256) {
            unsigned k = keys[t];
            bool ok = (shift == 24) ||
                      ((k >> (shift + 8)) == (prefix >> (shift + 8)));
            if (ok) atomicAdd(&hist[(k >> shift) & 255], 1);
        }
        __syncthreads();
        if (tid == 0) {
            int acc = 0, b = 255;
            for (; b > 0; --b) {
                if (acc + hist[b] >= need) break;
                acc += hist[b];
            }
            sneed = need - acc;
            sprefix = prefix | ((unsigned)b << shift);
        }
        __syncthreads();
        prefix = sprefix;
        need = sneed;
        __syncthreads();
    }
    const unsigned vkey = prefix;

    for (int t = tid; t < L_; t += 256) {
        unsigned k = keys[t];
        if (k > vkey) {
            int pos = atomicAdd(&cgt, 1);
            topidx[bh * U + pos] = t;
        } else if (k == vkey) {
            int p = atomicAdd(&ceq, 1);
            eqlist[p] = t;
        }
    }
    __syncthreads();
    const int s = ceq, r = need, base = U - r;
    for (int i = tid; i < s; i += 256) {
        int mine = eqlist[i], rank = 0;
        for (int j = 0; j < s; ++j) rank += (eqlist[j] < mine);
        if (rank < r) topidx[bh * U + base + rank] = mine;
    }
}

// ---- MFMA flash attention: all U queries of one (b,h) share each K/V tile ----
// T14 async-STAGE + T5 setprio (round-7 verified).
__global__ __launch_bounds__(256) void attn_mfma(const float* __restrict__ Q,
        const __hip_bfloat16* __restrict__ Kb, const __hip_bfloat16* __restrict__ Vb,
        const int* __restrict__ topidx,
        float* __restrict__ part_m, float* __restrict__ part_s,
        float* __restrict__ part_acc, int U) {
    __shared__ __align__(16) unsigned short Qh[QPAD * RS];
    __shared__ __align__(16) unsigned short Qm[QPAD * RS];
    __shared__ __align__(16) unsigned short Ks[64 * RS];
    __shared__ __align__(16) unsigned short Vt[64 * RS];
    __shared__ __align__(16) unsigned short Ph[QPAD * RS];

    const int c = blockIdx.x, h = blockIdx.y, b = blockIdx.z;
    const int bh = b * H_ + h;
    const int tid = threadIdx.x;
    const int wave = tid >> 6, lane = tid & 63;
    const int w16 = wave * 16;
    const int fr = lane & 15;
    const int quad = lane >> 4;
    const int fk = quad * 8;
    const int l0 = c * (L_ / NC);

    {
        int u = tid >> 2;
        int d0 = (tid & 3) * 16;
        unsigned short hbuf[16], mbuf[16];
        if (u < U) {
            int row = topidx[bh * U + u];
            const float* qp = Q + ((size_t)b * L_ + row) * D_ + h * 64 + d0;
            #pragma unroll
            for (int i = 0; i < 16; ++i) {
                float v = qp[i] * SCALE;
                unsigned short hb = bfbits(v);
                hbuf[i] = hb;
                mbuf[i] = bfbits(v - bf2f(hb));
            }
        } else {
            #pragma unroll
            for (int i = 0; i < 16; ++i) { hbuf[i] = 0; mbuf[i] = 0; }
        }
        #pragma unroll
        for (int i = 0; i < 2; ++i) {
            *(uint4*)&Qh[u * RS + d0 + i * 8] = ((uint4*)hbuf)[i];
            *(uint4*)&Qm[u * RS + d0 + i * 8] = ((uint4*)mbuf)[i];
        }
    }

    const int kkey = tid >> 3, kd0 = (tid & 7) * 8;
    const int vkey = tid >> 2, vd0 = (tid & 3) * 16;
    const __hip_bfloat16* kbase = Kb + ((size_t)b * L_ + l0) * D_ + h * 64;
    const __hip_bfloat16* vbase = Vb + ((size_t)b * L_ + l0) * D_ + h * 64;

    uint4 kr0, kr1, vr0, vr1;
    auto loadKV = [&](int t) {
        const __hip_bfloat16* kp = kbase + (size_t)t * 64 * D_;
        const __hip_bfloat16* vp = vbase + (size_t)t * 64 * D_ + (size_t)vkey * D_ + vd0;
        kr0 = *(const uint4*)(kp + (size_t)kkey * D_ + kd0);
        kr1 = *(const uint4*)(kp + (size_t)(kkey + 32) * D_ + kd0);
        vr0 = *(const uint4*)(vp);
        vr1 = *(const uint4*)(vp + 8);
    };
    auto writeKV = [&]() {
        *(uint4*)&Ks[kkey * RS + kd0] = kr0;
        *(uint4*)&Ks[(kkey + 32) * RS + kd0] = kr1;
        unsigned short vb_[16];
        *(uint4*)&vb_[0] = vr0;
        *(uint4*)&vb_[8] = vr1;
        #pragma unroll
        for (int i = 0; i < 16; ++i) Vt[(vd0 + i) * RS + vkey] = vb_[i];
    };

    float m_r[4], s_r[4];
    f32x4 acc_o[4];
    #pragma unroll
    for (int r = 0; r < 4; ++r) { m_r[r] = -INFINITY; s_r[r] = 0.f; }
    #pragma unroll
    for (int n = 0; n < 4; ++n) acc_o[n] = (f32x4){0.f, 0.f, 0.f, 0.f};

    loadKV(0);
    writeKV();
    __syncthreads();

    const int NT = (L_ / NC) / 64;
    for (int t = 0; t < NT; ++t) {
        if (t + 1 < NT) loadKV(t + 1);

        f32x4 sacc[4];
        __builtin_amdgcn_s_setprio(1);
        #pragma unroll
        for (int n = 0; n < 4; ++n) {
            sacc[n] = (f32x4){0.f, 0.f, 0.f, 0.f};
            #pragma unroll
            for (int ks = 0; ks < 2; ++ks) {
                int k0 = ks * 32;
                bf16x8 ah = *(const bf16x8*)&Qh[(w16 + fr) * RS + k0 + fk];
                bf16x8 am = *(const bf16x8*)&Qm[(w16 + fr) * RS + k0 + fk];
                bf16x8 bb = *(const bf16x8*)&Ks[(n * 16 + fr) * RS + k0 + fk];
                sacc[n] = __builtin_amdgcn_mfma_f32_16x16x32_bf16(ah, bb, sacc[n], 0, 0, 0);
                sacc[n] = __builtin_amdgcn_mfma_f32_16x16x32_bf16(am, bb, sacc[n], 0, 0, 0);
            }
        }
        __builtin_amdgcn_s_setprio(0);

        float p[4][4];
        #pragma unroll
        for (int r = 0; r < 4; ++r) {
            float rowmax = fmaxf(fmaxf(sacc[0][r], sacc[1][r]),
                                 fmaxf(sacc[2][r], sacc[3][r]));
            #pragma unroll
            for (int msk = 1; msk <= 8; msk <<= 1)
                rowmax = fmaxf(rowmax, __shfl_xor(rowmax, msk, 64));
            float mnew = fmaxf(m_r[r], rowmax);
            float alpha = __expf(m_r[r] - mnew);
            float rowsum = 0.f;
            #pragma unroll
            for (int n = 0; n < 4; ++n) {
                p[n][r] = __expf(sacc[n][r] - mnew);
                rowsum += p[n][r];
            }
            #pragma unroll
            for (int msk = 1; msk <= 8; msk <<= 1)
                rowsum += __shfl_xor(rowsum, msk, 64);
            s_r[r] = s_r[r] * alpha + rowsum;
            m_r[r] = mnew;
            #pragma unroll
            for (int n = 0; n < 4; ++n) acc_o[n][r] *= alpha;
        }

        #pragma unroll
        for (int r = 0; r < 4; ++r)
            #pragma unroll
            for (int n = 0; n < 4; ++n)
                Ph[(w16 + quad * 4 + r) * RS + n * 16 + fr] = bfbits(p[n][r]);

        __builtin_amdgcn_s_setprio(1);
        #pragma unroll
        for (int n = 0; n < 4; ++n) {
            #pragma unroll
            for (int ks = 0; ks < 2; ++ks) {
                int k0 = ks * 32;
                bf16x8 pa = *(const bf16x8*)&Ph[(w16 + fr) * RS + k0 + fk];
                bf16x8 vb = *(const bf16x8*)&Vt[(n * 16 + fr) * RS + k0 + fk];
                acc_o[n] = __builtin_amdgcn_mfma_f32_16x16x32_bf16(pa, vb, acc_o[n], 0, 0, 0);
            }
        }
        __builtin_amdgcn_s_setprio(0);

        if (t + 1 < NT) {
            __syncthreads();
            writeKV();
            __syncthreads();
        }
    }

    #pragma unroll
    for (int r = 0; r < 4; ++r) {
        int q = w16 + quad * 4 + r;
        if (q < U) {
            size_t base = ((size_t)(bh * QPAD + q)) * NC + c;
            if (fr == 0) { part_m[base] = m_r[r]; part_s[base] = s_r[r]; }
            #pragma unroll
            for (int n = 0; n < 4; ++n)
                part_acc[base * 64 + n * 16 + fr] = acc_o[n][r];
        }
    }
}

// ---- merge NC chunk partials -> ctx_top ----
__global__ __launch_bounds__(64) void attn_combine(const float* __restrict__ part_m,
        const float* __restrict__ part_s, const float* __restrict__ part_acc,
        float* __restrict__ ctx_top, int U) {
    int u = blockIdx.x, h = blockIdx.y, b = blockIdx.z;
    int bh = b * H_ + h;
    int d = threadIdx.x;
    size_t base = ((size_t)(bh * QPAD + u)) * NC;
    float M = -INFINITY;
    #pragma unroll
    for (int c = 0; c < NC; ++c) M = fmaxf(M, part_m[base + c]);
    float S = 0.f, A = 0.f;
    #pragma unroll
    for (int c = 0; c < NC; ++c) {
        float f = __expf(part_m[base + c] - M);
        S += part_s[base + c] * f;
        A += part_acc[(base + c) * 64 + d] * f;
    }
    ctx_top[(((size_t)bh) * U + u) * 64 + d] = A / S;
}

// ---- out[b][l][:] = base[b][:] ----
__global__ __launch_bounds__(256) void fill_base_kernel(const float* __restrict__ base,
                                                        float* __restrict__ out) {
    size_t i = (size_t)blockIdx.x * 256 + threadIdx.x;
    int col4 = (int)(i & 255);
    int b = (int)(i >> 21);
    ((float4*)out)[i] = ((const float4*)base)[b * 256 + col4];
}

// ---- out[b][row][:] += (ctx_top - vmean_h) @ Wo_h.T ----
__global__ __launch_bounds__(256) void delta_kernel(const float* __restrict__ ctx_top,
        const float* __restrict__ vmean, const float* __restrict__ Wo,
        const int* __restrict__ topidx, float* __restrict__ out, int U) {
    __shared__ float cd[64];
    int u = blockIdx.x, h = blockIdx.y, b = blockIdx.z;
    int row = topidx[(b * H_ + h) * U + u];
    if (threadIdx.x < 64) {
        cd[threadIdx.x] = ctx_top[(((size_t)(b * H_ + h)) * U + u) * 64 + threadIdx.x]
                        - vmean[b * D_ + h * 64 + threadIdx.x];
    }
    __syncthreads();
    float* op = out + ((size_t)b * L_ + row) * D_;
    #pragma unroll
    for (int r = 0; r < 4; ++r) {
        int j = r * 256 + threadIdx.x;
        const float* wr = Wo + (size_t)j * D_ + h * 64;
        float dlt = 0.f;
        #pragma unroll
        for (int k = 0; k < 64; k += 4) {
            float4 w4 = *(const float4*)(wr + k);
            dlt += cd[k] * w4.x + cd[k + 1] * w4.y + cd[k + 2] * w4.z + cd[k + 3] * w4.w;
        }
        atomicAdd(op + j, dlt);
    }
}

extern "C" void kernel_launch(void* const* d_in, const int* in_sizes, int n_in,
                              void* d_out, int out_size, void* d_ws, size_t ws_size,
                              hipStream_t stream) {
    const float* x   = (const float*)d_in[0];
    const float* Wq  = (const float*)d_in[1];
    const float* bq  = (const float*)d_in[2];
    const float* Wk  = (const float*)d_in[3];
    const float* bk  = (const float*)d_in[4];
    const float* Wv  = (const float*)d_in[5];
    const float* bv  = (const float*)d_in[6];
    const float* Wo  = (const float*)d_in[7];
    const float* bo  = (const float*)d_in[8];
    const int* idx_k = (const int*)d_in[9];
    const int U = in_sizes[9];
    float* out = (float*)d_out;
    (void)n_in; (void)ws_size;

    char* ws = (char*)d_ws;
    size_t off = 0;
    auto alloc = [&](size_t bytes) -> void* {
        void* p = ws + off;
        off += (bytes + 255) & ~(size_t)255;
        return p;
    };
    float* Q              = (float*)alloc((size_t)B_ * L_ * D_ * 4);
    __hip_bfloat16* Kb    = (__hip_bfloat16*)alloc((size_t)B_ * L_ * D_ * 2);
    __hip_bfloat16* Vb    = (__hip_bfloat16*)alloc((size_t)B_ * L_ * D_ * 2);
    unsigned short* xh    = (unsigned short*)alloc((size_t)B_ * L_ * D_ * 2);
    unsigned short* xm    = (unsigned short*)alloc((size_t)B_ * L_ * D_ * 2);
    unsigned short* xl    = (unsigned short*)alloc((size_t)B_ * L_ * D_ * 2);
    unsigned short* wqh   = (unsigned short*)alloc((size_t)D_ * D_ * 2);
    unsigned short* wqm   = (unsigned short*)alloc((size_t)D_ * D_ * 2);
    unsigned short* wql   = (unsigned short*)alloc((size_t)D_ * D_ * 2);
    unsigned short* wkh   = (unsigned short*)alloc((size_t)D_ * D_ * 2);
    unsigned short* wkm   = (unsigned short*)alloc((size_t)D_ * D_ * 2);
    unsigned short* wvh   = (unsigned short*)alloc((size_t)D_ * D_ * 2);
    unsigned short* wvm   = (unsigned short*)alloc((size_t)D_ * D_ * 2);
    float* Ksamp          = (float*)alloc((size_t)B_ * 64 * D_ * 4);
    float* Mbuf           = (float*)alloc((size_t)B_ * H_ * L_ * 4);
    int*   topidx         = (int*)alloc((size_t)B_ * H_ * 64 * 4);
    float* xmean          = (float*)alloc((size_t)B_ * D_ * 4);
    float* vmean          = (float*)alloc((size_t)B_ * D_ * 4);
    float* base           = (float*)alloc((size_t)B_ * D_ * 4);
    float* ctxt           = (float*)alloc((size_t)B_ * H_ * 64 * 64 * 4);
    float* part_m         = (float*)alloc((size_t)B_ * H_ * QPAD * NC * 4);
    float* part_s         = (float*)alloc((size_t)B_ * H_ * QPAD * NC * 4);
    float* part_acc       = (float*)alloc((size_t)B_ * H_ * QPAD * NC * 64 * 4);

    hipMemsetAsync(xmean, 0, (size_t)B_ * D_ * 4, stream);
    xmean_kernel<<<dim3(32, 4, B_), 256, 0, stream>>>(x, xmean);
    vecmat_kernel<<<dim3(4, B_), 256, 0, stream>>>(xmean, Wv, bv, vmean);
    vecmat_kernel<<<dim3(4, B_), 256, 0, stream>>>(vmean, Wo, bo, base);
    ksamp_kernel<<<dim3(U, B_, 4), 256, 0, stream>>>(x, Wk, bk, idx_k, Ksamp, U);

    const int n4x = B_ * L_ * D_ / 4;
    const int n4w = D_ * D_ / 4;
    split3_kernel<<<dim3(n4x / 256), 256, 0, stream>>>(x, xh, xm, xl, n4x);
    split3_kernel<<<dim3(n4w / 256), 256, 0, stream>>>(Wq, wqh, wqm, wql, n4w);
    split2_kernel<<<dim3(n4w / 256), 256, 0, stream>>>(Wk, wkh, wkm, n4w);
    split2_kernel<<<dim3(n4w / 256), 256, 0, stream>>>(Wv, wvh, wvm, n4w);

    qkv_mfma<<<dim3(24, 256), 256, 0, stream>>>(xh, xm, xl, wqh, wqm, wql,
                                                wkh, wkm, wvh, wvm,
                                                bq, bk, bv, Q, Kb, Vb);

    m_kernel<<<dim3(32, H_, B_), 256, 0, stream>>>(Q, Ksamp, Mbuf, U);
    topk_kernel<<<dim3(B_ * H_), 256, 0, stream>>>(Mbuf, topidx, U);
    attn_mfma<<<dim3(NC, H_, B_), 256, 0, stream>>>(Q, Kb, Vb, topidx,
                                                    part_m, part_s, part_acc, U);
    attn_combine<<<dim3(U, H_, B_), 64, 0, stream>>>(part_m, part_s, part_acc, ctxt, U);
    fill_base_kernel<<<dim3(out_size / 4 / 256), 256, 0, stream>>>(base, out);
    delta_kernel<<<dim3(U, H_, B_), 256, 0, stream>>>(ctxt, vmean, Wo, topidx, out, U);
}